// Round 10
// baseline (810.676 us; speedup 1.0000x reference)
//
#include <hip/hip_runtime.h>

#define S_LEN 1024
#define DMODEL 512
#define NHEADS 8
#define DHEAD 64
#define HDIM 2048
#define WIN 64

typedef _Float16 f16x8 __attribute__((ext_vector_type(8)));
typedef _Float16 f16x4 __attribute__((ext_vector_type(4)));
typedef _Float16 f16x2 __attribute__((ext_vector_type(2)));
typedef float f32x4 __attribute__((ext_vector_type(4)));
typedef float f32x16 __attribute__((ext_vector_type(16)));

__device__ __forceinline__ void stage16(const _Float16* g, _Float16* l) {
  __builtin_amdgcn_global_load_lds((const __attribute__((address_space(1))) unsigned int*)g,
                                   (__attribute__((address_space(3))) unsigned int*)l, 16, 0, 0);
}

// ---------------- weight prep: f32 -> f16 (QKV concat, FC1, FC2, out_w) --------
__global__ void wprep_kernel(const float* __restrict__ wq, const float* __restrict__ wk,
                             const float* __restrict__ wv, const float* __restrict__ bq,
                             const float* __restrict__ bk, const float* __restrict__ bv,
                             const float* __restrict__ w1, const float* __restrict__ w2,
                             const float* __restrict__ wo,
                             _Float16* __restrict__ Wqkv, float* __restrict__ bqkv,
                             _Float16* __restrict__ W1h, _Float16* __restrict__ W2h,
                             _Float16* __restrict__ Woh) {
  int i = blockIdx.x * 256 + threadIdx.x;
  if (i < 262144) {
    Wqkv[i]          = (_Float16)wq[i];
    Wqkv[262144 + i] = (_Float16)wk[i];
    Wqkv[524288 + i] = (_Float16)wv[i];
  }
  if (i < 1048576) {
    W1h[i] = (_Float16)w1[i];
    W2h[i] = (_Float16)w2[i];
    Woh[i]           = (_Float16)wo[i];
    Woh[1048576 + i] = (_Float16)wo[1048576 + i];
    Woh[2097152 + i] = (_Float16)wo[2097152 + i];
  }
  if (i < 512) { bqkv[i] = bq[i]; bqkv[512 + i] = bk[i]; bqkv[1024 + i] = bv[i]; }
}

// ---------------- embed + positional encoding (f16 out) + VS zero ----------------
__global__ void embed_pe_kernel(const int* __restrict__ inputs, const float* __restrict__ emb,
                                _Float16* __restrict__ Xb, float* __restrict__ VS) {
  int row = blockIdx.x;          // b*S + s
  int s = row & (S_LEN - 1);
  int t = threadIdx.x;           // pair index 0..255
  if (row < 16) VS[row * 256 + t] = 0.0f;
  int tok = inputs[row];
  float dv = __expf(-logf(10000.0f) * (2.0f * (float)t) / (float)DMODEL);
  float ang = (float)s * dv;
  float sv = sinf(ang);
  float cv = cosf(ang);
  size_t base = (size_t)row * DMODEL + 2 * t;
  float x0 = emb[(size_t)tok * DMODEL + 2 * t] + sv;
  float x1 = emb[(size_t)tok * DMODEL + 2 * t + 1] + cv;
  f16x2 h; h[0] = (_Float16)x0; h[1] = (_Float16)x1;
  *(f16x2*)(Xb + base) = h;
}

// ---------------- MFMA f16 GEMM, 2-phase dbuf, TRANSPOSED epilogue -------------
// 256 thr, 4 waves 2x2, 128x128 tile, BK=32, 4x4 frags of 16x16x32.
// Operand-swapped MFMA: acc=mfma(bf,af) => lane holds output row=l15, 4
// consecutive cols (l4*4+j) => packed f16x4/float4 stores (no write amplification).
#define EPI_RELU16 1
#define EPI_QKV 3
#define EPI_PART 4

template <int EPI>
__launch_bounds__(256)
__global__ void mfma_gemm(const _Float16* __restrict__ A, const _Float16* __restrict__ W,
                          const float* __restrict__ bias,
                          float* __restrict__ Pf0, float* __restrict__ Pf1,
                          _Float16* __restrict__ Ch, float* __restrict__ VS,
                          int M, int N, int Kstride, int Kslice) {
  __shared__ _Float16 As[2][128 * 32];
  __shared__ _Float16 Bs[2][128 * 32];
  const int bm = blockIdx.x * 128;
  const int bn = blockIdx.y * 128;
  const int z = blockIdx.z;
  const int t = threadIdx.x;
  const int lane = t & 63;
  const int w = t >> 6;
  const int wr = w >> 1, wc = w & 1;
  const int l15 = lane & 15, l4 = lane >> 4;

  const int idx0 = t, idx1 = t + 256;
  const int r0 = idx0 >> 2, kg0 = (idx0 & 3) << 3;
  const int r1 = idx1 >> 2, kg1 = (idx1 & 3) << 3;
  const _Float16* Ag0 = A + (size_t)(bm + r0) * Kstride + kg0;
  const _Float16* Ag1 = A + (size_t)(bm + r1) * Kstride + kg1;
  const _Float16* Wg0 = W + (size_t)(bn + r0) * Kstride + kg0;
  const _Float16* Wg1 = W + (size_t)(bn + r1) * Kstride + kg1;

  const int kbeg = z * Kslice;
  const int nsteps = Kslice >> 5;

  // prologue: stage step 0 into buffer 0
  stage16(Ag0 + kbeg, As[0] + idx0 * 8);
  stage16(Ag1 + kbeg, As[0] + idx1 * 8);
  stage16(Wg0 + kbeg, Bs[0] + idx0 * 8);
  stage16(Wg1 + kbeg, Bs[0] + idx1 * 8);
  __syncthreads();

  f32x4 acc[4][4] = {};
  int cur = 0;
  for (int s = 0; s < nsteps; ++s) {
    if (s + 1 < nsteps) {          // issue next-tile loads first (overlap compute)
      int kn = kbeg + (s + 1) * 32;
      stage16(Ag0 + kn, As[cur ^ 1] + idx0 * 8);
      stage16(Ag1 + kn, As[cur ^ 1] + idx1 * 8);
      stage16(Wg0 + kn, Bs[cur ^ 1] + idx0 * 8);
      stage16(Wg1 + kn, Bs[cur ^ 1] + idx1 * 8);
    }
    f16x8 af[4], bf[4];
#pragma unroll
    for (int m = 0; m < 4; ++m)
      af[m] = *(const f16x8*)&As[cur][(wr * 64 + m * 16 + l15) * 32 + l4 * 8];
#pragma unroll
    for (int n = 0; n < 4; ++n)
      bf[n] = *(const f16x8*)&Bs[cur][(wc * 64 + n * 16 + l15) * 32 + l4 * 8];
#pragma unroll
    for (int m = 0; m < 4; ++m)
#pragma unroll
      for (int n = 0; n < 4; ++n)   // swapped operands: transposed D fragment
        acc[m][n] = __builtin_amdgcn_mfma_f32_16x16x32_f16(bf[n], af[m], acc[m][n], 0, 0, 0);
    __syncthreads();               // drains vmcnt (next tile ready) + lgkm
    cur ^= 1;
  }

  // transposed epilogue: lane -> row = ...+l15, cols = ...+l4*4+{0..3}
  float cs[4][4] = {{0.f}};
#pragma unroll
  for (int m = 0; m < 4; ++m) {
    int row = bm + wr * 64 + m * 16 + l15;
#pragma unroll
    for (int n = 0; n < 4; ++n) {
      int colbase = bn + wc * 64 + n * 16 + l4 * 4;
      size_t off = (size_t)row * N + colbase;
      if (EPI == EPI_PART) {
        float4 o;
        o.x = acc[m][n][0]; o.y = acc[m][n][1];
        o.z = acc[m][n][2]; o.w = acc[m][n][3];
        if (z == 0) *(float4*)(Pf0 + off) = o;
        else        *(float4*)(Pf1 + off) = o;
      } else {
        float4 bb = *(const float4*)(bias + colbase);
        float v0 = acc[m][n][0] + bb.x;
        float v1 = acc[m][n][1] + bb.y;
        float v2 = acc[m][n][2] + bb.z;
        float v3 = acc[m][n][3] + bb.w;
        if (EPI == EPI_RELU16) {
          v0 = fmaxf(v0, 0.f); v1 = fmaxf(v1, 0.f);
          v2 = fmaxf(v2, 0.f); v3 = fmaxf(v3, 0.f);
        }
        if (EPI == EPI_QKV) {
          cs[n][0] += v0; cs[n][1] += v1; cs[n][2] += v2; cs[n][3] += v3;
        }
        f16x4 h;
        h[0] = (_Float16)v0; h[1] = (_Float16)v1;
        h[2] = (_Float16)v2; h[3] = (_Float16)v3;
        *(f16x4*)(Ch + off) = h;
      }
    }
  }
  if (EPI == EPI_QKV && bn >= 1024) {
    const int batch = bm >> 10;
#pragma unroll
    for (int n = 0; n < 4; ++n)
#pragma unroll
      for (int j = 0; j < 4; ++j) {
        float s = cs[n][j];
        s += __shfl_xor(s, 1); s += __shfl_xor(s, 2);
        s += __shfl_xor(s, 4); s += __shfl_xor(s, 8);
        if (l15 == 0) {
          int col = bn + wc * 64 + n * 16 + l4 * 4 + j;
          atomicAdd(&VS[batch * 512 + (col - 1024)], s);
        }
      }
  }
}

// ---------------- MFMA windowed attention, full-softmax zero correction --------
// grid (S/128, H, B) = (8,8,8); 256 threads = 4 waves, 32 queries per wave.
// Output f16 (feeds layernorm).
#define KTMAX 256
#define VTS 264   // Vt row stride (f16), 16B-aligned

__launch_bounds__(256)
__global__ void attn_kernel(const _Float16* __restrict__ QKVh, const float* __restrict__ VSg,
                            _Float16* __restrict__ O) {
  __shared__ _Float16 Ks[KTMAX * 64];      // row-major, XOR-swizzled cols, 32KB
  __shared__ _Float16 Vt[64 * VTS];        // transposed V, 33KB
  __shared__ float VsC[8][64];             // per-32-key-chunk V column sums

  const int qb0 = blockIdx.x * 128, h = blockIdx.y, b = blockIdx.z;
  const int jlo = max(0, qb0 - WIN);
  const int jhi = min(S_LEN, qb0 + 128 + WIN);
  const int KT = jhi - jlo;                 // 192 or 256, multiple of 32
  const int t = threadIdx.x;
  const int lane = t & 63, w = t >> 6;
  const int hi = lane >> 5, l31 = lane & 31;

  const _Float16* Kg = QKVh + ((size_t)(b * S_LEN + jlo)) * 1536 + 512 + h * 64;
#pragma unroll
  for (int p = 0; p < 8; ++p) {
    int u = t + p * 256;                    // 0..2047
    int row = u >> 3;
    int cb = (u & 7) * 16;                  // byte col within 128B row
    int rowc = min(row, KT - 1);
    int scb = cb ^ ((row & 7) << 4);
    stage16(Kg + (size_t)rowc * 1536 + (scb >> 1), Ks + u * 8);
  }
  const _Float16* Vg = QKVh + ((size_t)(b * S_LEN + jlo)) * 1536 + 1024 + h * 64;
#pragma unroll
  for (int p = 0; p < 8; ++p) {
    int u = t + p * 256;
    int row = u >> 3;                       // key 0..255
    int d0 = (u & 7) * 8;
    f16x8 v = {0, 0, 0, 0, 0, 0, 0, 0};
    if (row < KT) v = *(const f16x8*)(Vg + (size_t)row * 1536 + d0);
#pragma unroll
    for (int e = 0; e < 8; ++e) Vt[(d0 + e) * VTS + row] = v[e];
  }
  __syncthreads();
  for (int slot = t; slot < 512; slot += 256) {
    int c = slot >> 6, d = slot & 63;
    const f16x8* col = (const f16x8*)(Vt + d * VTS + c * 32);
    float s = 0.f;
#pragma unroll
    for (int g = 0; g < 4; ++g) {
      f16x8 v = col[g];
#pragma unroll
      for (int e = 0; e < 8; ++e) s += (float)v[e];
    }
    VsC[c][d] = s;
  }
  const int qw = qb0 + w * 32;
  const _Float16* Qg = QKVh + ((size_t)(b * S_LEN + qw + l31)) * 1536 + h * 64;
  f16x8 qf[4];
#pragma unroll
  for (int ds = 0; ds < 4; ++ds) qf[ds] = *(const f16x8*)(Qg + ds * 16 + hi * 8);
  __syncthreads();

  const int c0 = max(0, qw - WIN - jlo) >> 5;
  const int c1 = min(KT, qw + 96 - jlo) >> 5;   // exclusive
  const int nproc = (c1 - c0) * 32;
  const int i = qw + l31;
  const int wlo = i - WIN, whi = i + WIN;

  float m = 0.f, l = 0.f;
  f32x16 accA = {}, accB = {};

  union PK { f16x2 h; unsigned u; };
  union A8 { unsigned u[4]; f16x8 h; };

  for (int c = c0; c < c1; ++c) {
    const int kb = c * 32;
    f32x16 sf = {};
#pragma unroll
    for (int ds = 0; ds < 4; ++ds) {
      int row = kb + l31;
      int cbyte = ((ds * 16 + hi * 8) * 2) ^ ((row & 7) << 4);
      f16x8 kf = *(const f16x8*)((const char*)Ks + row * 128 + cbyte);
      sf = __builtin_amdgcn_mfma_f32_32x32x16_f16(kf, qf[ds], sf, 0, 0, 0);
    }
    float s[16]; float pm = -1e30f;
#pragma unroll
    for (int r = 0; r < 16; ++r) {
      int gk = jlo + kb + (r & 3) + 8 * (r >> 2) + 4 * hi;
      float v = (gk >= wlo && gk < whi) ? sf[r] * 0.125f : 0.f;
      s[r] = v;
      pm = fmaxf(pm, v);
    }
    pm = fmaxf(pm, __shfl_xor(pm, 32));
    if (!__all(pm <= m + 8.f)) {
      float mn = fmaxf(m, pm);
      float f = __expf(m - mn);
      l *= f;
#pragma unroll
      for (int r = 0; r < 16; ++r) {
        int q = (r & 3) + 8 * (r >> 2) + 4 * hi;
        float fr = __shfl(f, q);
        accA[r] *= fr; accB[r] *= fr;
      }
      m = mn;
    }
    float p[16]; float ls = 0.f;
#pragma unroll
    for (int r = 0; r < 16; ++r) { p[r] = __expf(s[r] - m); ls += p[r]; }
    l += ls;
    unsigned u[8], x[8];
#pragma unroll
    for (int kk = 0; kk < 8; ++kk) {
      PK cv; cv.h[0] = (_Float16)p[2 * kk]; cv.h[1] = (_Float16)p[2 * kk + 1];
      u[kk] = cv.u;
    }
#pragma unroll
    for (int kk = 0; kk < 8; ++kk) x[kk] = (unsigned)__shfl_xor((int)u[kk], 32);
    A8 a0, a1;
    a0.u[0] = hi ? x[2] : u[0]; a0.u[1] = hi ? x[3] : u[1];
    a0.u[2] = hi ? u[2] : x[0]; a0.u[3] = hi ? u[3] : x[1];
    a1.u[0] = hi ? x[6] : u[4]; a1.u[1] = hi ? x[7] : u[5];
    a1.u[2] = hi ? u[6] : x[4]; a1.u[3] = hi ? u[7] : x[5];
#pragma unroll
    for (int ks = 0; ks < 2; ++ks) {
      f16x8 pa = ks ? a1.h : a0.h;
      f16x8 v0 = *(const f16x8*)(Vt + (size_t)(l31) * VTS + kb + ks * 16 + hi * 8);
      f16x8 v1 = *(const f16x8*)(Vt + (size_t)(32 + l31) * VTS + kb + ks * 16 + hi * 8);
      accA = __builtin_amdgcn_mfma_f32_32x32x16_f16(pa, v0, accA, 0, 0, 0);
      accB = __builtin_amdgcn_mfma_f32_32x32x16_f16(pa, v1, accB, 0, 0, 0);
    }
  }

  l = l + __shfl_xor(l, 32);
  const int dA = l31, dB = 32 + l31;
  float vsA = 0.f, vsB = 0.f;
  for (int c = c0; c < c1; ++c) { vsA += VsC[c][dA]; vsB += VsC[c][dB]; }
  const float vtA = VSg[b * 512 + h * 64 + dA];
  const float vtB = VSg[b * 512 + h * 64 + dB];
  const float zcount = (float)(S_LEN - nproc);
#pragma unroll
  for (int r = 0; r < 16; ++r) {
    int q = (r & 3) + 8 * (r >> 2) + 4 * hi;
    float mq = __shfl(m, q);
    float lq = __shfl(l, q);
    float em = __expf(-mq);
    float denom = lq + zcount * em;
    float inv = 1.0f / denom;
    size_t rowbase = ((size_t)(b * S_LEN + qw + q)) * DMODEL + h * 64;
    O[rowbase + dA] = (_Float16)((accA[r] + em * (vtA - vsA)) * inv);
    O[rowbase + dB] = (_Float16)((accB[r] + em * (vtB - vsB)) * inv);
  }
}

// ---------------- layernorm over D=512 (f16 in, f16 out) ----------------
__global__ void ln_kernel(const _Float16* __restrict__ X, const float* __restrict__ g,
                          const float* __restrict__ be, _Float16* __restrict__ Yh) {
  int row = blockIdx.x;
  int t = threadIdx.x;
  f16x2 v2 = *(const f16x2*)(X + (size_t)row * DMODEL + 2 * t);
  float vx = (float)v2[0], vy = (float)v2[1];
  float s = vx + vy;
  float sq = vx * vx + vy * vy;
#pragma unroll
  for (int off = 32; off; off >>= 1) {
    s += __shfl_xor(s, off);
    sq += __shfl_xor(sq, off);
  }
  __shared__ float ss[4], sqq[4];
  int w = t >> 6, lane = t & 63;
  if (lane == 0) { ss[w] = s; sqq[w] = sq; }
  __syncthreads();
  s = ss[0] + ss[1] + ss[2] + ss[3];
  sq = sqq[0] + sqq[1] + sqq[2] + sqq[3];
  float mu = s * (1.0f / DMODEL);
  float var = sq * (1.0f / DMODEL) - mu * mu;
  float rstd = rsqrtf(var + 1e-5f);
  float g0 = g[2 * t], g1 = g[2 * t + 1];
  float b0 = be[2 * t], b1 = be[2 * t + 1];
  f16x2 hh;
  hh[0] = (_Float16)((vx - mu) * rstd * g0 + b0);
  hh[1] = (_Float16)((vy - mu) * rstd * g1 + b1);
  *(f16x2*)(Yh + (size_t)row * DMODEL + 2 * t) = hh;
}

// ---- fused split-K(2) reduce + bias + residual(f16) + layernorm (f16 out) + VS zero
__global__ void ln2_fused_kernel(const float* __restrict__ P0, const float* __restrict__ P1,
                                 const _Float16* __restrict__ XBb, const float* __restrict__ fb,
                                 const float* __restrict__ g, const float* __restrict__ be,
                                 _Float16* __restrict__ Yh, float* __restrict__ VS) {
  int row = blockIdx.x;
  int t = threadIdx.x;
  if (row < 16) VS[row * 256 + t] = 0.0f;     // VS for next iteration's QKV
  size_t off = (size_t)row * DMODEL + 2 * t;
  float2 p0 = *(const float2*)(P0 + off);
  float2 p1 = *(const float2*)(P1 + off);
  f16x2 xb = *(const f16x2*)(XBb + off);
  float vx = p0.x + p1.x + fb[2 * t]     + (float)xb[0];
  float vy = p0.y + p1.y + fb[2 * t + 1] + (float)xb[1];
  float s = vx + vy;
  float sq = vx * vx + vy * vy;
#pragma unroll
  for (int off2 = 32; off2; off2 >>= 1) {
    s += __shfl_xor(s, off2);
    sq += __shfl_xor(sq, off2);
  }
  __shared__ float ss[4], sqq[4];
  int w = t >> 6, lane = t & 63;
  if (lane == 0) { ss[w] = s; sqq[w] = sq; }
  __syncthreads();
  s = ss[0] + ss[1] + ss[2] + ss[3];
  sq = sqq[0] + sqq[1] + sqq[2] + sqq[3];
  float mu = s * (1.0f / DMODEL);
  float var = sq * (1.0f / DMODEL) - mu * mu;
  float rstd = rsqrtf(var + 1e-5f);
  float g0 = g[2 * t], g1 = g[2 * t + 1];
  float b0 = be[2 * t], b1 = be[2 * t + 1];
  f16x2 hh;
  hh[0] = (_Float16)((vx - mu) * rstd * g0 + b0);
  hh[1] = (_Float16)((vy - mu) * rstd * g1 + b1);
  *(f16x2*)(Yh + off) = hh;
}

// ---------------- final projection (f16, grid 32x6x8 = 1536 blocks) ------------
__global__ void outproj_partial_kernel(const _Float16* __restrict__ Xb,
                                       const _Float16* __restrict__ Woh,
                                       float* __restrict__ part) {
  const int KTOT = S_LEN * DMODEL;   // 524288
  const int CH = KTOT / 32;          // 16384
  int chunk = blockIdx.x, c = blockIdx.y, b = blockIdx.z;
  const int t = threadIdx.x;
  const _Float16* x = Xb + (size_t)b * KTOT + (size_t)chunk * CH;
  const _Float16* wv = Woh + (size_t)c * KTOT + (size_t)chunk * CH;
  float acc = 0.f;
#pragma unroll
  for (int p = 0; p < 8; ++p) {
    f16x8 a = *(const f16x8*)(x + (p * 256 + t) * 8);
    f16x8 w8 = *(const f16x8*)(wv + (p * 256 + t) * 8);
#pragma unroll
    for (int e = 0; e < 8; ++e) acc += (float)a[e] * (float)w8[e];
  }
#pragma unroll
  for (int off = 32; off; off >>= 1) acc += __shfl_xor(acc, off);
  __shared__ float red[4];
  int w = t >> 6, lane = t & 63;
  if (lane == 0) red[w] = acc;
  __syncthreads();
  if (t == 0)
    part[(b * 6 + c) * 32 + chunk] = red[0] + red[1] + red[2] + red[3];
}

__global__ void outproj_final_kernel(const float* __restrict__ part, const float* __restrict__ ob,
                                     float* __restrict__ out) {
  int idx = threadIdx.x;
  if (idx < 48) {
    float s = 0.f;
#pragma unroll
    for (int k = 0; k < 32; ++k) s += part[idx * 32 + k];
    out[idx] = s + ob[idx % 6];
  }
}

extern "C" void kernel_launch(void* const* d_in, const int* in_sizes, int n_in,
                              void* d_out, int out_size, void* d_ws, size_t ws_size,
                              hipStream_t stream) {
  (void)in_sizes; (void)n_in; (void)out_size; (void)ws_size;
  const int*   inputs = (const int*)  d_in[0];
  const float* emb    = (const float*)d_in[1];
  const float* wq     = (const float*)d_in[2];
  const float* bq     = (const float*)d_in[3];
  const float* wk     = (const float*)d_in[4];
  const float* bk     = (const float*)d_in[5];
  const float* wv     = (const float*)d_in[6];
  const float* bv     = (const float*)d_in[7];
  const float* ln_g   = (const float*)d_in[8];
  const float* ln_b   = (const float*)d_in[9];
  const float* fc1_w  = (const float*)d_in[10];
  const float* fc1_b  = (const float*)d_in[11];
  const float* fc2_w  = (const float*)d_in[12];
  const float* fc2_b  = (const float*)d_in[13];
  const float* out_w  = (const float*)d_in[14];
  const float* out_b  = (const float*)d_in[15];
  float* out = (float*)d_out;

  char* p = (char*)d_ws;
  float*    P0   = (float*)p;      p += (size_t)8192 * 512 * 4;   // 16 MB
  _Float16* Xb   = (_Float16*)p;   p += (size_t)8192 * 512 * 2;   //  8 MB
  _Float16* QKVh = (_Float16*)p;   p += (size_t)8192 * 1536 * 2;  // 24 MB (= P1 region)
  _Float16* XBb  = (_Float16*)p;   p += (size_t)8192 * 512 * 2;   //  8 MB
  _Float16* H    = (_Float16*)p;   p += (size_t)8192 * 2048 * 2;  // 32 MB
  _Float16* Abh  = H;                                             // aliases H (dead by FC1)
  _Float16* Wqkv = (_Float16*)p;   p += (size_t)1536 * 512 * 2;
  _Float16* W1h  = (_Float16*)p;   p += (size_t)2048 * 512 * 2;
  _Float16* W2h  = (_Float16*)p;   p += (size_t)512 * 2048 * 2;
  _Float16* Woh  = (_Float16*)p;   p += (size_t)6 * 524288 * 2;   // 6.3 MB
  float*    bqkv = (float*)p;      p += 1536 * 4;
  float*    VS   = (float*)p;      p += 4096 * 4;
  float*    part = (float*)p;      p += 1536 * 4;
  float*    P1   = (float*)QKVh;      // QKV dead after attn; FC2 runs later

  wprep_kernel<<<4096, 256, 0, stream>>>(wq, wk, wv, bq, bk, bv, fc1_w, fc2_w, out_w,
                                         Wqkv, bqkv, W1h, W2h, Woh);
  embed_pe_kernel<<<8192, 256, 0, stream>>>(inputs, emb, Xb, VS);
  for (int it = 0; it < 6; ++it) {
    mfma_gemm<EPI_QKV><<<dim3(64, 12), 256, 0, stream>>>(Xb, Wqkv, bqkv,
        nullptr, nullptr, QKVh, VS, 8192, 1536, 512, 512);
    attn_kernel<<<dim3(8, 8, 8), 256, 0, stream>>>(QKVh, VS, Abh);
    ln_kernel<<<8192, 256, 0, stream>>>(Abh, ln_g, ln_b, XBb);
    mfma_gemm<EPI_RELU16><<<dim3(64, 16), 256, 0, stream>>>(XBb, W1h, fc1_b,
        nullptr, nullptr, H, nullptr, 8192, 2048, 512, 512);
    mfma_gemm<EPI_PART><<<dim3(64, 4, 2), 256, 0, stream>>>(H, W2h, nullptr,
        P0, P1, nullptr, nullptr, 8192, 512, 2048, 1024);
    ln2_fused_kernel<<<8192, 256, 0, stream>>>(P0, P1, XBb, fc2_b,
                                               ln_g, ln_b, Xb, VS);
  }
  outproj_partial_kernel<<<dim3(32, 6, 8), 256, 0, stream>>>(Xb, Woh, part);
  outproj_final_kernel<<<1, 64, 0, stream>>>(part, out_b, out);
}

// Round 11
// 748.509 us; speedup vs baseline: 1.0831x; 1.0831x over previous
//
#include <hip/hip_runtime.h>

#define S_LEN 1024
#define DMODEL 512
#define NHEADS 8
#define DHEAD 64
#define HDIM 2048
#define WIN 64

typedef _Float16 f16x8 __attribute__((ext_vector_type(8)));
typedef _Float16 f16x2 __attribute__((ext_vector_type(2)));
typedef float f32x4 __attribute__((ext_vector_type(4)));
typedef float f32x16 __attribute__((ext_vector_type(16)));

__device__ __forceinline__ void stage16(const _Float16* g, _Float16* l) {
  __builtin_amdgcn_global_load_lds((const __attribute__((address_space(1))) unsigned int*)g,
                                   (__attribute__((address_space(3))) unsigned int*)l, 16, 0, 0);
}

// ---------------- weight prep: f32 -> f16 (QKV concat, FC1, FC2, out_w) --------
__global__ void wprep_kernel(const float* __restrict__ wq, const float* __restrict__ wk,
                             const float* __restrict__ wv, const float* __restrict__ bq,
                             const float* __restrict__ bk, const float* __restrict__ bv,
                             const float* __restrict__ w1, const float* __restrict__ w2,
                             const float* __restrict__ wo,
                             _Float16* __restrict__ Wqkv, float* __restrict__ bqkv,
                             _Float16* __restrict__ W1h, _Float16* __restrict__ W2h,
                             _Float16* __restrict__ Woh) {
  int i = blockIdx.x * 256 + threadIdx.x;
  if (i < 262144) {
    Wqkv[i]          = (_Float16)wq[i];
    Wqkv[262144 + i] = (_Float16)wk[i];
    Wqkv[524288 + i] = (_Float16)wv[i];
  }
  if (i < 1048576) {
    W1h[i] = (_Float16)w1[i];
    W2h[i] = (_Float16)w2[i];
    Woh[i]           = (_Float16)wo[i];
    Woh[1048576 + i] = (_Float16)wo[1048576 + i];
    Woh[2097152 + i] = (_Float16)wo[2097152 + i];
  }
  if (i < 512) { bqkv[i] = bq[i]; bqkv[512 + i] = bk[i]; bqkv[1024 + i] = bv[i]; }
}

// ---------------- embed + positional encoding (f16 out) + VS zero ----------------
__global__ void embed_pe_kernel(const int* __restrict__ inputs, const float* __restrict__ emb,
                                _Float16* __restrict__ Xb, float* __restrict__ VS) {
  int row = blockIdx.x;          // b*S + s
  int s = row & (S_LEN - 1);
  int t = threadIdx.x;           // pair index 0..255
  if (row < 16) VS[row * 256 + t] = 0.0f;
  int tok = inputs[row];
  float dv = __expf(-logf(10000.0f) * (2.0f * (float)t) / (float)DMODEL);
  float ang = (float)s * dv;
  float sv = sinf(ang);
  float cv = cosf(ang);
  size_t base = (size_t)row * DMODEL + 2 * t;
  float x0 = emb[(size_t)tok * DMODEL + 2 * t] + sv;
  float x1 = emb[(size_t)tok * DMODEL + 2 * t + 1] + cv;
  f16x2 h; h[0] = (_Float16)x0; h[1] = (_Float16)x1;
  *(f16x2*)(Xb + base) = h;
}

// ---------------- MFMA f16 GEMM, 2-phase double-buffered (round-6/9 proven) ----
// 256 thr, 4 waves 2x2, 128x128 tile, BK=32, 4x4 frags of 16x16x32.
// EPI: 1 relu->f16, 3 ->f16 + V-colsum atomics (QKV), 4 split-K f32 partial (z=0/1)
#define EPI_RELU16 1
#define EPI_QKV 3
#define EPI_PART 4

template <int EPI>
__launch_bounds__(256)
__global__ void mfma_gemm(const _Float16* __restrict__ A, const _Float16* __restrict__ W,
                          const float* __restrict__ bias,
                          float* __restrict__ Pf0, float* __restrict__ Pf1,
                          _Float16* __restrict__ Ch, float* __restrict__ VS,
                          int M, int N, int Kstride, int Kslice) {
  __shared__ _Float16 As[2][128 * 32];
  __shared__ _Float16 Bs[2][128 * 32];
  const int bm = blockIdx.x * 128;
  const int bn = blockIdx.y * 128;
  const int z = blockIdx.z;
  const int t = threadIdx.x;
  const int lane = t & 63;
  const int w = t >> 6;
  const int wr = w >> 1, wc = w & 1;
  const int l15 = lane & 15, l4 = lane >> 4;

  const int idx0 = t, idx1 = t + 256;
  const int r0 = idx0 >> 2, kg0 = (idx0 & 3) << 3;
  const int r1 = idx1 >> 2, kg1 = (idx1 & 3) << 3;
  const _Float16* Ag0 = A + (size_t)(bm + r0) * Kstride + kg0;
  const _Float16* Ag1 = A + (size_t)(bm + r1) * Kstride + kg1;
  const _Float16* Wg0 = W + (size_t)(bn + r0) * Kstride + kg0;
  const _Float16* Wg1 = W + (size_t)(bn + r1) * Kstride + kg1;

  const int kbeg = z * Kslice;
  const int nsteps = Kslice >> 5;

  // prologue: stage step 0 into buffer 0
  stage16(Ag0 + kbeg, As[0] + idx0 * 8);
  stage16(Ag1 + kbeg, As[0] + idx1 * 8);
  stage16(Wg0 + kbeg, Bs[0] + idx0 * 8);
  stage16(Wg1 + kbeg, Bs[0] + idx1 * 8);
  __syncthreads();

  f32x4 acc[4][4] = {};
  int cur = 0;
  for (int s = 0; s < nsteps; ++s) {
    if (s + 1 < nsteps) {          // issue next-tile loads first (overlap compute)
      int kn = kbeg + (s + 1) * 32;
      stage16(Ag0 + kn, As[cur ^ 1] + idx0 * 8);
      stage16(Ag1 + kn, As[cur ^ 1] + idx1 * 8);
      stage16(Wg0 + kn, Bs[cur ^ 1] + idx0 * 8);
      stage16(Wg1 + kn, Bs[cur ^ 1] + idx1 * 8);
    }
    f16x8 af[4], bf[4];
#pragma unroll
    for (int m = 0; m < 4; ++m)
      af[m] = *(const f16x8*)&As[cur][(wr * 64 + m * 16 + l15) * 32 + l4 * 8];
#pragma unroll
    for (int n = 0; n < 4; ++n)
      bf[n] = *(const f16x8*)&Bs[cur][(wc * 64 + n * 16 + l15) * 32 + l4 * 8];
#pragma unroll
    for (int m = 0; m < 4; ++m)
#pragma unroll
      for (int n = 0; n < 4; ++n)
        acc[m][n] = __builtin_amdgcn_mfma_f32_16x16x32_f16(af[m], bf[n], acc[m][n], 0, 0, 0);
    __syncthreads();               // drains vmcnt (next tile ready) + lgkm
    cur ^= 1;
  }

  float cs[4] = {0.f, 0.f, 0.f, 0.f};
#pragma unroll
  for (int n = 0; n < 4; ++n) {
    int col = bn + wc * 64 + n * 16 + l15;
    float bb = (EPI == EPI_PART) ? 0.f : bias[col];
#pragma unroll
    for (int m = 0; m < 4; ++m) {
      int row = bm + wr * 64 + m * 16 + l4 * 4;
#pragma unroll
      for (int j = 0; j < 4; ++j) {
        float v = acc[m][n][j] + bb;
        size_t off = (size_t)(row + j) * N + col;
        if (EPI == EPI_RELU16) {
          Ch[off] = (_Float16)fmaxf(v, 0.0f);
        } else if (EPI == EPI_QKV) {
          Ch[off] = (_Float16)v;
          cs[n] += v;
        } else {  // EPI_PART
          if (z == 0) Pf0[off] = v;
          else Pf1[off] = v;
        }
      }
    }
  }
  if (EPI == EPI_QKV && bn >= 1024) {
    const int batch = bm >> 10;
#pragma unroll
    for (int n = 0; n < 4; ++n) {
      float s = cs[n];
      s += __shfl_xor(s, 16);
      s += __shfl_xor(s, 32);
      if (l4 == 0) {
        int col = bn + wc * 64 + n * 16 + l15;
        atomicAdd(&VS[batch * 512 + (col - 1024)], s);
      }
    }
  }
}

// ---------------- MFMA windowed attention, full-softmax zero correction --------
// grid (S/128, H, B) = (8,8,8); 256 threads = 4 waves, 32 queries per wave.
// Output f16 (feeds layernorm).
#define KTMAX 256
#define VTS 264   // Vt row stride (f16), 16B-aligned

__launch_bounds__(256)
__global__ void attn_kernel(const _Float16* __restrict__ QKVh, const float* __restrict__ VSg,
                            _Float16* __restrict__ O) {
  __shared__ _Float16 Ks[KTMAX * 64];      // row-major, XOR-swizzled cols, 32KB
  __shared__ _Float16 Vt[64 * VTS];        // transposed V, 33KB
  __shared__ float VsC[8][64];             // per-32-key-chunk V column sums

  const int qb0 = blockIdx.x * 128, h = blockIdx.y, b = blockIdx.z;
  const int jlo = max(0, qb0 - WIN);
  const int jhi = min(S_LEN, qb0 + 128 + WIN);
  const int KT = jhi - jlo;                 // 192 or 256, multiple of 32
  const int t = threadIdx.x;
  const int lane = t & 63, w = t >> 6;
  const int hi = lane >> 5, l31 = lane & 31;

  const _Float16* Kg = QKVh + ((size_t)(b * S_LEN + jlo)) * 1536 + 512 + h * 64;
#pragma unroll
  for (int p = 0; p < 8; ++p) {
    int u = t + p * 256;                    // 0..2047
    int row = u >> 3;
    int cb = (u & 7) * 16;                  // byte col within 128B row
    int rowc = min(row, KT - 1);
    int scb = cb ^ ((row & 7) << 4);
    stage16(Kg + (size_t)rowc * 1536 + (scb >> 1), Ks + u * 8);
  }
  const _Float16* Vg = QKVh + ((size_t)(b * S_LEN + jlo)) * 1536 + 1024 + h * 64;
#pragma unroll
  for (int p = 0; p < 8; ++p) {
    int u = t + p * 256;
    int row = u >> 3;                       // key 0..255
    int d0 = (u & 7) * 8;
    f16x8 v = {0, 0, 0, 0, 0, 0, 0, 0};
    if (row < KT) v = *(const f16x8*)(Vg + (size_t)row * 1536 + d0);
#pragma unroll
    for (int e = 0; e < 8; ++e) Vt[(d0 + e) * VTS + row] = v[e];
  }
  __syncthreads();
  for (int slot = t; slot < 512; slot += 256) {
    int c = slot >> 6, d = slot & 63;
    const f16x8* col = (const f16x8*)(Vt + d * VTS + c * 32);
    float s = 0.f;
#pragma unroll
    for (int g = 0; g < 4; ++g) {
      f16x8 v = col[g];
#pragma unroll
      for (int e = 0; e < 8; ++e) s += (float)v[e];
    }
    VsC[c][d] = s;
  }
  const int qw = qb0 + w * 32;
  const _Float16* Qg = QKVh + ((size_t)(b * S_LEN + qw + l31)) * 1536 + h * 64;
  f16x8 qf[4];
#pragma unroll
  for (int ds = 0; ds < 4; ++ds) qf[ds] = *(const f16x8*)(Qg + ds * 16 + hi * 8);
  __syncthreads();

  const int c0 = max(0, qw - WIN - jlo) >> 5;
  const int c1 = min(KT, qw + 96 - jlo) >> 5;   // exclusive
  const int nproc = (c1 - c0) * 32;
  const int i = qw + l31;
  const int wlo = i - WIN, whi = i + WIN;

  float m = 0.f, l = 0.f;
  f32x16 accA = {}, accB = {};

  union PK { f16x2 h; unsigned u; };
  union A8 { unsigned u[4]; f16x8 h; };

  for (int c = c0; c < c1; ++c) {
    const int kb = c * 32;
    f32x16 sf = {};
#pragma unroll
    for (int ds = 0; ds < 4; ++ds) {
      int row = kb + l31;
      int cbyte = ((ds * 16 + hi * 8) * 2) ^ ((row & 7) << 4);
      f16x8 kf = *(const f16x8*)((const char*)Ks + row * 128 + cbyte);
      sf = __builtin_amdgcn_mfma_f32_32x32x16_f16(kf, qf[ds], sf, 0, 0, 0);
    }
    float s[16]; float pm = -1e30f;
#pragma unroll
    for (int r = 0; r < 16; ++r) {
      int gk = jlo + kb + (r & 3) + 8 * (r >> 2) + 4 * hi;
      float v = (gk >= wlo && gk < whi) ? sf[r] * 0.125f : 0.f;
      s[r] = v;
      pm = fmaxf(pm, v);
    }
    pm = fmaxf(pm, __shfl_xor(pm, 32));
    if (!__all(pm <= m + 8.f)) {
      float mn = fmaxf(m, pm);
      float f = __expf(m - mn);
      l *= f;
#pragma unroll
      for (int r = 0; r < 16; ++r) {
        int q = (r & 3) + 8 * (r >> 2) + 4 * hi;
        float fr = __shfl(f, q);
        accA[r] *= fr; accB[r] *= fr;
      }
      m = mn;
    }
    float p[16]; float ls = 0.f;
#pragma unroll
    for (int r = 0; r < 16; ++r) { p[r] = __expf(s[r] - m); ls += p[r]; }
    l += ls;
    unsigned u[8], x[8];
#pragma unroll
    for (int kk = 0; kk < 8; ++kk) {
      PK cv; cv.h[0] = (_Float16)p[2 * kk]; cv.h[1] = (_Float16)p[2 * kk + 1];
      u[kk] = cv.u;
    }
#pragma unroll
    for (int kk = 0; kk < 8; ++kk) x[kk] = (unsigned)__shfl_xor((int)u[kk], 32);
    A8 a0, a1;
    a0.u[0] = hi ? x[2] : u[0]; a0.u[1] = hi ? x[3] : u[1];
    a0.u[2] = hi ? u[2] : x[0]; a0.u[3] = hi ? u[3] : x[1];
    a1.u[0] = hi ? x[6] : u[4]; a1.u[1] = hi ? x[7] : u[5];
    a1.u[2] = hi ? u[6] : x[4]; a1.u[3] = hi ? u[7] : x[5];
#pragma unroll
    for (int ks = 0; ks < 2; ++ks) {
      f16x8 pa = ks ? a1.h : a0.h;
      f16x8 v0 = *(const f16x8*)(Vt + (size_t)(l31) * VTS + kb + ks * 16 + hi * 8);
      f16x8 v1 = *(const f16x8*)(Vt + (size_t)(32 + l31) * VTS + kb + ks * 16 + hi * 8);
      accA = __builtin_amdgcn_mfma_f32_32x32x16_f16(pa, v0, accA, 0, 0, 0);
      accB = __builtin_amdgcn_mfma_f32_32x32x16_f16(pa, v1, accB, 0, 0, 0);
    }
  }

  l = l + __shfl_xor(l, 32);
  const int dA = l31, dB = 32 + l31;
  float vsA = 0.f, vsB = 0.f;
  for (int c = c0; c < c1; ++c) { vsA += VsC[c][dA]; vsB += VsC[c][dB]; }
  const float vtA = VSg[b * 512 + h * 64 + dA];
  const float vtB = VSg[b * 512 + h * 64 + dB];
  const float zcount = (float)(S_LEN - nproc);
#pragma unroll
  for (int r = 0; r < 16; ++r) {
    int q = (r & 3) + 8 * (r >> 2) + 4 * hi;
    float mq = __shfl(m, q);
    float lq = __shfl(l, q);
    float em = __expf(-mq);
    float denom = lq + zcount * em;
    float inv = 1.0f / denom;
    size_t rowbase = ((size_t)(b * S_LEN + qw + q)) * DMODEL + h * 64;
    O[rowbase + dA] = (_Float16)((accA[r] + em * (vtA - vsA)) * inv);
    O[rowbase + dB] = (_Float16)((accB[r] + em * (vtB - vsB)) * inv);
  }
}

// ---------------- layernorm over D=512 (f16 in, f16 out) ----------------
__global__ void ln_kernel(const _Float16* __restrict__ X, const float* __restrict__ g,
                          const float* __restrict__ be, _Float16* __restrict__ Yh) {
  int row = blockIdx.x;
  int t = threadIdx.x;
  f16x2 v2 = *(const f16x2*)(X + (size_t)row * DMODEL + 2 * t);
  float vx = (float)v2[0], vy = (float)v2[1];
  float s = vx + vy;
  float sq = vx * vx + vy * vy;
#pragma unroll
  for (int off = 32; off; off >>= 1) {
    s += __shfl_xor(s, off);
    sq += __shfl_xor(sq, off);
  }
  __shared__ float ss[4], sqq[4];
  int w = t >> 6, lane = t & 63;
  if (lane == 0) { ss[w] = s; sqq[w] = sq; }
  __syncthreads();
  s = ss[0] + ss[1] + ss[2] + ss[3];
  sq = sqq[0] + sqq[1] + sqq[2] + sqq[3];
  float mu = s * (1.0f / DMODEL);
  float var = sq * (1.0f / DMODEL) - mu * mu;
  float rstd = rsqrtf(var + 1e-5f);
  float g0 = g[2 * t], g1 = g[2 * t + 1];
  float b0 = be[2 * t], b1 = be[2 * t + 1];
  f16x2 hh;
  hh[0] = (_Float16)((vx - mu) * rstd * g0 + b0);
  hh[1] = (_Float16)((vy - mu) * rstd * g1 + b1);
  *(f16x2*)(Yh + (size_t)row * DMODEL + 2 * t) = hh;
}

// ---- fused split-K(2) reduce + bias + residual(f16) + layernorm (f16 out) + VS zero
__global__ void ln2_fused_kernel(const float* __restrict__ P0, const float* __restrict__ P1,
                                 const _Float16* __restrict__ XBb, const float* __restrict__ fb,
                                 const float* __restrict__ g, const float* __restrict__ be,
                                 _Float16* __restrict__ Yh, float* __restrict__ VS) {
  int row = blockIdx.x;
  int t = threadIdx.x;
  if (row < 16) VS[row * 256 + t] = 0.0f;     // VS for next iteration's QKV
  size_t off = (size_t)row * DMODEL + 2 * t;
  float2 p0 = *(const float2*)(P0 + off);
  float2 p1 = *(const float2*)(P1 + off);
  f16x2 xb = *(const f16x2*)(XBb + off);
  float vx = p0.x + p1.x + fb[2 * t]     + (float)xb[0];
  float vy = p0.y + p1.y + fb[2 * t + 1] + (float)xb[1];
  float s = vx + vy;
  float sq = vx * vx + vy * vy;
#pragma unroll
  for (int off2 = 32; off2; off2 >>= 1) {
    s += __shfl_xor(s, off2);
    sq += __shfl_xor(sq, off2);
  }
  __shared__ float ss[4], sqq[4];
  int w = t >> 6, lane = t & 63;
  if (lane == 0) { ss[w] = s; sqq[w] = sq; }
  __syncthreads();
  s = ss[0] + ss[1] + ss[2] + ss[3];
  sq = sqq[0] + sqq[1] + sqq[2] + sqq[3];
  float mu = s * (1.0f / DMODEL);
  float var = sq * (1.0f / DMODEL) - mu * mu;
  float rstd = rsqrtf(var + 1e-5f);
  float g0 = g[2 * t], g1 = g[2 * t + 1];
  float b0 = be[2 * t], b1 = be[2 * t + 1];
  f16x2 hh;
  hh[0] = (_Float16)((vx - mu) * rstd * g0 + b0);
  hh[1] = (_Float16)((vy - mu) * rstd * g1 + b1);
  *(f16x2*)(Yh + off) = hh;
}

// ---------------- final projection (f16, grid 32x6x8 = 1536 blocks) ------------
__global__ void outproj_partial_kernel(const _Float16* __restrict__ Xb,
                                       const _Float16* __restrict__ Woh,
                                       float* __restrict__ part) {
  const int KTOT = S_LEN * DMODEL;   // 524288
  const int CH = KTOT / 32;          // 16384
  int chunk = blockIdx.x, c = blockIdx.y, b = blockIdx.z;
  const int t = threadIdx.x;
  const _Float16* x = Xb + (size_t)b * KTOT + (size_t)chunk * CH;
  const _Float16* wv = Woh + (size_t)c * KTOT + (size_t)chunk * CH;
  float acc = 0.f;
#pragma unroll
  for (int p = 0; p < 8; ++p) {
    f16x8 a = *(const f16x8*)(x + (p * 256 + t) * 8);
    f16x8 w8 = *(const f16x8*)(wv + (p * 256 + t) * 8);
#pragma unroll
    for (int e = 0; e < 8; ++e) acc += (float)a[e] * (float)w8[e];
  }
#pragma unroll
  for (int off = 32; off; off >>= 1) acc += __shfl_xor(acc, off);
  __shared__ float red[4];
  int w = t >> 6, lane = t & 63;
  if (lane == 0) red[w] = acc;
  __syncthreads();
  if (t == 0)
    part[(b * 6 + c) * 32 + chunk] = red[0] + red[1] + red[2] + red[3];
}

__global__ void outproj_final_kernel(const float* __restrict__ part, const float* __restrict__ ob,
                                     float* __restrict__ out) {
  int idx = threadIdx.x;
  if (idx < 48) {
    float s = 0.f;
#pragma unroll
    for (int k = 0; k < 32; ++k) s += part[idx * 32 + k];
    out[idx] = s + ob[idx % 6];
  }
}

extern "C" void kernel_launch(void* const* d_in, const int* in_sizes, int n_in,
                              void* d_out, int out_size, void* d_ws, size_t ws_size,
                              hipStream_t stream) {
  (void)in_sizes; (void)n_in; (void)out_size; (void)ws_size;
  const int*   inputs = (const int*)  d_in[0];
  const float* emb    = (const float*)d_in[1];
  const float* wq     = (const float*)d_in[2];
  const float* bq     = (const float*)d_in[3];
  const float* wk     = (const float*)d_in[4];
  const float* bk     = (const float*)d_in[5];
  const float* wv     = (const float*)d_in[6];
  const float* bv     = (const float*)d_in[7];
  const float* ln_g   = (const float*)d_in[8];
  const float* ln_b   = (const float*)d_in[9];
  const float* fc1_w  = (const float*)d_in[10];
  const float* fc1_b  = (const float*)d_in[11];
  const float* fc2_w  = (const float*)d_in[12];
  const float* fc2_b  = (const float*)d_in[13];
  const float* out_w  = (const float*)d_in[14];
  const float* out_b  = (const float*)d_in[15];
  float* out = (float*)d_out;

  char* p = (char*)d_ws;
  float*    P0   = (float*)p;      p += (size_t)8192 * 512 * 4;   // 16 MB
  _Float16* Xb   = (_Float16*)p;   p += (size_t)8192 * 512 * 2;   //  8 MB
  _Float16* QKVh = (_Float16*)p;   p += (size_t)8192 * 1536 * 2;  // 24 MB (= P1 region)
  _Float16* XBb  = (_Float16*)p;   p += (size_t)8192 * 512 * 2;   //  8 MB
  _Float16* H    = (_Float16*)p;   p += (size_t)8192 * 2048 * 2;  // 32 MB
  _Float16* Abh  = H;                                             // aliases H (dead by FC1)
  _Float16* Wqkv = (_Float16*)p;   p += (size_t)1536 * 512 * 2;
  _Float16* W1h  = (_Float16*)p;   p += (size_t)2048 * 512 * 2;
  _Float16* W2h  = (_Float16*)p;   p += (size_t)512 * 2048 * 2;
  _Float16* Woh  = (_Float16*)p;   p += (size_t)6 * 524288 * 2;   // 6.3 MB
  float*    bqkv = (float*)p;      p += 1536 * 4;
  float*    VS   = (float*)p;      p += 4096 * 4;
  float*    part = (float*)p;      p += 1536 * 4;
  float*    P1   = (float*)QKVh;      // QKV dead after attn; FC2 runs later

  wprep_kernel<<<4096, 256, 0, stream>>>(wq, wk, wv, bq, bk, bv, fc1_w, fc2_w, out_w,
                                         Wqkv, bqkv, W1h, W2h, Woh);
  embed_pe_kernel<<<8192, 256, 0, stream>>>(inputs, emb, Xb, VS);
  for (int it = 0; it < 6; ++it) {
    mfma_gemm<EPI_QKV><<<dim3(64, 12), 256, 0, stream>>>(Xb, Wqkv, bqkv,
        nullptr, nullptr, QKVh, VS, 8192, 1536, 512, 512);
    attn_kernel<<<dim3(8, 8, 8), 256, 0, stream>>>(QKVh, VS, Abh);
    ln_kernel<<<8192, 256, 0, stream>>>(Abh, ln_g, ln_b, XBb);
    mfma_gemm<EPI_RELU16><<<dim3(64, 16), 256, 0, stream>>>(XBb, W1h, fc1_b,
        nullptr, nullptr, H, nullptr, 8192, 2048, 512, 512);
    mfma_gemm<EPI_PART><<<dim3(64, 4, 2), 256, 0, stream>>>(H, W2h, nullptr,
        P0, P1, nullptr, nullptr, 8192, 512, 2048, 1024);
    ln2_fused_kernel<<<8192, 256, 0, stream>>>(P0, P1, XBb, fc2_b,
                                               ln_g, ln_b, Xb, VS);
  }
  outproj_partial_kernel<<<dim3(32, 6, 8), 256, 0, stream>>>(Xb, Woh, part);
  outproj_final_kernel<<<1, 64, 0, stream>>>(part, out_b, out);
}